// Round 14
// baseline (338.738 us; speedup 1.0000x reference)
//
#include <hip/hip_runtime.h>

#define HH 192
#define WW 192
#define CC 64
#define NB 1024
#define SS 32

typedef __bf16 bf16x8 __attribute__((ext_vector_type(8)));
typedef float  f32x4  __attribute__((ext_vector_type(4)));

__device__ __forceinline__ unsigned short f2bf(float f) {
    unsigned int u = __builtin_bit_cast(unsigned int, f);
    u += 0x7FFFu + ((u >> 16) & 1u);   // round-to-nearest-even
    return (unsigned short)(u >> 16);
}

// Bijective XCD-chunked work mapping (T1). Each XCD gets a CONTIGUOUS work
// range -> tiles of one box (and, with the sort below, boxes of one image)
// stay on one XCD's L2.
__device__ __forceinline__ int xcd_swizzle(int id, int total) {
    int q = total >> 3, r = total & 7;
    if (r == 0) return (id & 7) * q + (id >> 3);
    return id;   // non-multiple-of-8 fallback (not hit with our grids)
}

// ---------------------------------------------------------------------------
// Counting sort of boxes by image id (box_ids in [0,B)): perm[sorted] = box.
// Work-reordering only — every box processed once, outputs written to the
// true index, so results are independent of the (atomic, nondeterministic)
// rank order within a bin. 1 block x 1024 threads.
// ---------------------------------------------------------------------------
__global__ __launch_bounds__(1024) void sort_kernel(const int* __restrict__ box_ids,
                                                    int* __restrict__ perm) {
    __shared__ int cnt[8];
    __shared__ int base[8];
    int t = threadIdx.x;
    if (t < 8) cnt[t] = 0;
    __syncthreads();
    int b = box_ids[t] & 7;
    int rank = atomicAdd(&cnt[b], 1);
    __syncthreads();
    if (t == 0) {
        int s = 0;
        for (int i = 0; i < 8; i++) { base[i] = s; s += cnt[i]; }
    }
    __syncthreads();
    perm[base[b] + rank] = t;
}

// ---------------------------------------------------------------------------
// Merged weight prep (single launch, 324 blocks x 256 thr):
//  blocks [0,144): conv1 w -> WT1;  [144,288): conv2 w -> WT2;
//  blocks [288,324): out w -> WTo (cols padded to 16).
// WT[tap][kc][nt][lane][j], c = kc*32 + (lane>>4)*8 + j, o = nt*16 + (lane&15)
// ---------------------------------------------------------------------------
__global__ __launch_bounds__(256) void wprep_kernel(
        const float* __restrict__ c1w, const float* __restrict__ c2w,
        const float* __restrict__ ow, unsigned short* __restrict__ wt1,
        unsigned short* __restrict__ wt2, unsigned short* __restrict__ wto) {
    int b = blockIdx.x;
    if (b < 288) {
        const float* w = (b < 144) ? c1w : c2w;
        unsigned short* wt = (b < 144) ? wt1 : wt2;
        int idx = (b < 144 ? b : b - 144) * 256 + threadIdx.x;   // 0 .. 36863
        int j    = idx & 7;
        int lane = (idx >> 3) & 63;
        int nt   = (idx >> 9) & 3;
        int kc   = (idx >> 11) & 1;
        int tap  = idx >> 12;
        int c = kc * 32 + ((lane >> 4) << 3) + j;
        int o = (nt << 4) + (lane & 15);
        wt[idx] = f2bf(w[(tap * 64 + c) * 64 + o]);
    } else {
        int idx = (b - 288) * 256 + threadIdx.x;                 // 0 .. 9215
        int j    = idx & 7;
        int lane = (idx >> 3) & 63;
        int kc   = (idx >> 9) & 1;
        int tap  = idx >> 10;
        int c = kc * 32 + ((lane >> 4) << 3) + j;
        int o = lane & 15;
        wto[idx] = (o < 3) ? f2bf(ow[(tap * 64 + c) * 3 + o]) : (unsigned short)0;
    }
}

// ---------------------------------------------------------------------------
// FUSED crop + conv1. Swizzled zero-conflict LDS ([10][32][64]) padded to
// 46080 B -> 3 blocks/CU. XCD-chunked 1D work mapping + image-sorted box
// order (perm): each XCD gathers from ~1 feature image (L2-local).
// bufA indexed by SORTED position nl (consumer uses the same convention).
// ---------------------------------------------------------------------------
#define CROP_ELEMS (10 * 32 * 64)
__global__ __launch_bounds__(256, 3) void crop_conv1_kernel(
        const float* __restrict__ feat, const float* __restrict__ boxes,
        const int* __restrict__ box_ids, const int* __restrict__ perm,
        const unsigned short* __restrict__ wt,
        const float* __restrict__ bias, unsigned short* __restrict__ out,
        int n0, int nblk) {
    // 40960 B used + 5120 B pad = 46080 B -> exactly 3 blocks/CU
    __shared__ unsigned short s_in[CROP_ELEMS + 2560];

    int wid = xcd_swizzle(blockIdx.x, nblk);
    int nl = wid >> 2;
    int y0 = (wid & 3) << 3;
    int gn = perm[n0 + nl];          // true box index (image-sorted order)
    int t = threadIdx.x;
    int wave = t >> 6, lane = t & 63;
    int quad = lane >> 4, mcol = lane & 15;

    // ---- crop stage: rows y0-1 .. y0+8 (zeros outside [0,32)), swizzled ----
    {
        int px = t >> 3, cg = t & 7, c0 = cg << 3;
        float by1 = boxes[gn * 4 + 0];
        float bx1 = boxes[gn * 4 + 1];
        float by2 = boxes[gn * 4 + 2];
        float bx2 = boxes[gn * 4 + 3];
        float tx = (float)px / 31.0f;
        float xs = (bx1 + tx * (bx2 - bx1)) * 191.0f;
        float x0f = fminf(fmaxf(floorf(xs), 0.0f), 191.0f);
        float wx = xs - x0f;
        int x0i = (int)x0f, x1i = min(x0i + 1, 191);
        const float* fb = feat + (size_t)box_ids[gn] * (HH * WW * CC);
        unsigned short* dst = s_in + (px << 6) + ((cg ^ (px & 7)) << 3);
#pragma unroll 2
        for (int r = 0; r < 10; r++) {
            int gy = y0 + r - 1;
            uint4 v = {0, 0, 0, 0};
            if (gy >= 0 && gy < 32) {
                float ty = (float)gy / 31.0f;
                float ys = (by1 + ty * (by2 - by1)) * 191.0f;
                float y0f = fminf(fmaxf(floorf(ys), 0.0f), 191.0f);
                float wy = ys - y0f;
                int y0i = (int)y0f, y1i = min(y0i + 1, 191);
                const float* p00 = fb + ((size_t)y0i * WW + x0i) * CC + c0;
                const float* p01 = fb + ((size_t)y0i * WW + x1i) * CC + c0;
                const float* p10 = fb + ((size_t)y1i * WW + x0i) * CC + c0;
                const float* p11 = fb + ((size_t)y1i * WW + x1i) * CC + c0;
                unsigned int rr[4];
#pragma unroll
                for (int h = 0; h < 2; h++) {
                    float4 v00 = *(const float4*)(p00 + 4 * h);
                    float4 v01 = *(const float4*)(p01 + 4 * h);
                    float4 v10 = *(const float4*)(p10 + 4 * h);
                    float4 v11 = *(const float4*)(p11 + 4 * h);
                    const float* a00 = (const float*)&v00;
                    const float* a01 = (const float*)&v01;
                    const float* a10 = (const float*)&v10;
                    const float* a11 = (const float*)&v11;
#pragma unroll
                    for (int i = 0; i < 4; i++) {
                        float top = a00[i] + wx * (a01[i] - a00[i]);
                        float bot = a10[i] + wx * (a11[i] - a10[i]);
                        float val = top + wy * (bot - top);
                        unsigned short bb = f2bf(val);
                        int e = 4 * h + i;
                        if (e & 1) rr[e >> 1] |= ((unsigned int)bb << 16);
                        else       rr[e >> 1]  = (unsigned int)bb;
                    }
                }
                v = *(uint4*)rr;
            }
            *(uint4*)(dst + (r << 11)) = v;
        }
    }
    __syncthreads();

    // ---- conv1 MFMA (swizzled a-frag reads, zero-conflict) ----
    f32x4 acc[4][4];
#pragma unroll
    for (int nt = 0; nt < 4; nt++) {
        float bv = bias[(nt << 4) + mcol];
#pragma unroll
        for (int mi = 0; mi < 4; mi++) acc[mi][nt] = (f32x4){bv, bv, bv, bv};
    }

    int r0 = wave << 1;
#pragma unroll
    for (int dy = 0; dy < 3; dy++) {
#pragma unroll
        for (int dx = 0; dx < 3; dx++) {
            int tap = dy * 3 + dx;
#pragma unroll
            for (int kc = 0; kc < 2; kc++) {
                int cslot = (kc << 2) + quad;
                uint4 bfr[4];
#pragma unroll
                for (int nt = 0; nt < 4; nt++)
                    bfr[nt] = *(const uint4*)(wt + ((((tap * 2 + kc) * 4 + nt) * 64 + lane) << 3));
                uint4 afr[4];
#pragma unroll
                for (int mi = 0; mi < 4; mi++) {
                    int xs = ((mi & 1) << 4) + mcol + dx - 1;
                    uint4 a = {0, 0, 0, 0};
                    if (xs >= 0 && xs < 32)
                        a = *(const uint4*)(s_in + (((r0 + (mi >> 1) + dy) * 32 + xs) << 6) +
                                            ((cslot ^ (xs & 7)) << 3));
                    afr[mi] = a;
                }
#pragma unroll
                for (int mi = 0; mi < 4; mi++)
#pragma unroll
                    for (int nt = 0; nt < 4; nt++)
                        acc[mi][nt] = __builtin_amdgcn_mfma_f32_16x16x32_bf16(
                            __builtin_bit_cast(bf16x8, afr[mi]),
                            __builtin_bit_cast(bf16x8, bfr[nt]), acc[mi][nt], 0, 0, 0);
            }
        }
    }

    // epilogue: scattered 2B stores (no write amplification at 3 blk/CU);
    // bufA indexed by SORTED position nl
#pragma unroll
    for (int mi = 0; mi < 4; mi++) {
        int yy = y0 + r0 + (mi >> 1);
        int xb = ((mi & 1) << 4) + (quad << 2);
#pragma unroll
        for (int reg = 0; reg < 4; reg++) {
            unsigned short* op = out + (((size_t)nl * 32 + yy) * 32 + (xb + reg)) * 64 + mcol;
#pragma unroll
            for (int nt = 0; nt < 4; nt++) {
                float v = fmaxf(acc[mi][nt][reg], 0.0f);
                op[nt << 4] = f2bf(v);
            }
        }
    }
}

// ---------------------------------------------------------------------------
// FUSED conv2 + outconv — r7 structure (256 thr / 4 waves, 57344 B -> 2 blk/CU,
// zero-conflict swizzled LDS), XCD-chunked mapping; reads bufA by SORTED
// position nl, resolves true box via perm for cls/output.
// ---------------------------------------------------------------------------
#define S_IN_ELEMS (12 * 32 * 64)
__global__ __launch_bounds__(256, 2) void conv2_out_kernel(
        const unsigned short* __restrict__ in, const unsigned short* __restrict__ wt,
        const float* __restrict__ bias, const unsigned short* __restrict__ wto,
        const float* __restrict__ ob, const int* __restrict__ cls,
        const int* __restrict__ perm, float* __restrict__ out, int n0, int nblk) {
    // 49152 B used + 8192 B pad = 57344 B -> exactly 2 blocks/CU
    __shared__ unsigned short s_in[S_IN_ELEMS + 4096];

    int wid = xcd_swizzle(blockIdx.x, nblk);
    int nl = wid >> 2;
    int y0 = (wid & 3) << 3;
    int t = threadIdx.x;
    int wave = t >> 6, lane = t & 63;
    int quad = lane >> 4, mcol = lane & 15;

    // ---- stage conv1 rows y0-1 .. y0+10 (zeros outside [0,32)), swizzled ----
    {
        int px = t >> 3, cg = t & 7;
        const unsigned short* src = in + (((size_t)nl * 32) * 32 + px) * 64 + (cg << 3);
        unsigned short* dst = s_in + (px << 6) + ((cg ^ (px & 7)) << 3);
#pragma unroll
        for (int r = 0; r < 12; r++) {
            int gy = y0 + r - 1;
            uint4 v = {0, 0, 0, 0};
            if (gy >= 0 && gy < 32) v = *(const uint4*)(src + (size_t)gy * 2048);
            *(uint4*)(dst + (r << 11)) = v;
        }
    }
    __syncthreads();

    // ---- conv2 (SAME, 64->64): 20 m-tiles = 10 rows x 2 col-halves;
    //      wave w handles mt = 5w .. 5w+4 (lr = mt>>1, col-half h = mt&1) ----
    float bv[4];
#pragma unroll
    for (int nt = 0; nt < 4; nt++) bv[nt] = bias[(nt << 4) + mcol];

    f32x4 acc[5][4];
#pragma unroll
    for (int i = 0; i < 5; i++)
#pragma unroll
        for (int nt = 0; nt < 4; nt++)
            acc[i][nt] = (f32x4){bv[nt], bv[nt], bv[nt], bv[nt]};

    int mt0 = wave * 5;
#pragma unroll
    for (int dy = 0; dy < 3; dy++) {
#pragma unroll
        for (int dx = 0; dx < 3; dx++) {
            int tap = dy * 3 + dx;
#pragma unroll
            for (int kc = 0; kc < 2; kc++) {
                int cslot = (kc << 2) + quad;
                uint4 bfr[4];
#pragma unroll
                for (int nt = 0; nt < 4; nt++)
                    bfr[nt] = *(const uint4*)(wt + ((((tap * 2 + kc) * 4 + nt) * 64 + lane) << 3));
#pragma unroll
                for (int i = 0; i < 5; i++) {
                    int mt = mt0 + i;
                    int lr = mt >> 1, h = mt & 1;
                    int xs = (h << 4) + mcol + dx - 1;
                    uint4 a = {0, 0, 0, 0};
                    if (xs >= 0 && xs < 32)
                        a = *(const uint4*)(s_in + (((lr + dy) * 32 + xs) << 6) +
                                            ((cslot ^ (xs & 7)) << 3));
#pragma unroll
                    for (int nt = 0; nt < 4; nt++)
                        acc[i][nt] = __builtin_amdgcn_mfma_f32_16x16x32_bf16(
                            __builtin_bit_cast(bf16x8, a),
                            __builtin_bit_cast(bf16x8, bfr[nt]), acc[i][nt], 0, 0, 0);
                }
            }
        }
    }
    __syncthreads();   // all conv2 LDS reads done; safe to repurpose s_in

    // ---- write ReLU'd conv2 bf16 into s_in rows 0..9 (swizzled) ----
#pragma unroll
    for (int i = 0; i < 5; i++) {
        int mt = mt0 + i;
        int lr = mt >> 1, h = mt & 1;
        int xb = (h << 4) + (quad << 2);
#pragma unroll
        for (int reg = 0; reg < 4; reg++) {
            int px = xb + reg;
#pragma unroll
            for (int nt = 0; nt < 4; nt++) {
                int oc = (nt << 4) + mcol;
                float v = fmaxf(acc[i][nt][reg], 0.0f);
                s_in[((lr * 32 + px) << 6) + (((oc >> 3) ^ (px & 7)) << 3) + (oc & 7)] = f2bf(v);
            }
        }
    }
    __syncthreads();

    // ---- outconv (VALID, 64->3 padded 16) from s_in rows 0..9 ----
    f32x4 acc2[4];
#pragma unroll
    for (int mi = 0; mi < 4; mi++) acc2[mi] = (f32x4){0.f, 0.f, 0.f, 0.f};

    int r0 = wave << 1;
#pragma unroll
    for (int dy = 0; dy < 3; dy++) {
#pragma unroll
        for (int dx = 0; dx < 3; dx++) {
            int tap = dy * 3 + dx;
#pragma unroll
            for (int kc = 0; kc < 2; kc++) {
                int cslot = (kc << 2) + quad;
                uint4 bfr = *(const uint4*)(wto + (((tap * 2 + kc) * 64 + lane) << 3));
#pragma unroll
                for (int mi = 0; mi < 4; mi++) {
                    int xs = ((mi & 1) << 4) + mcol + dx;     // VALID: 0..33
                    if (xs > 31) xs = 31;                     // clamped lanes feed x>=30 (discarded)
                    uint4 a = *(const uint4*)(s_in + (((r0 + (mi >> 1) + dy) * 32 + xs) << 6) +
                                              ((cslot ^ (xs & 7)) << 3));
                    acc2[mi] = __builtin_amdgcn_mfma_f32_16x16x32_bf16(
                        __builtin_bit_cast(bf16x8, a),
                        __builtin_bit_cast(bf16x8, bfr), acc2[mi], 0, 0, 0);
                }
            }
        }
    }

    int gn = perm[n0 + nl];          // true box index
    int oc = cls[gn];
    if (mcol == oc) {
        float obv = ob[oc];
#pragma unroll
        for (int mi = 0; mi < 4; mi++) {
            int yy = y0 + r0 + (mi >> 1);
            int xb = ((mi & 1) << 4) + (quad << 2);
            if (yy < 30) {
#pragma unroll
                for (int reg = 0; reg < 4; reg++) {
                    int x = xb + reg;
                    if (x < 30)
                        out[(size_t)gn * 900 + yy * 30 + x] = acc2[mi][reg] + obv;
                }
            }
        }
    }
}

// ---------------------------------------------------------------------------
extern "C" void kernel_launch(void* const* d_in, const int* in_sizes, int n_in,
                              void* d_out, int out_size, void* d_ws, size_t ws_size,
                              hipStream_t stream) {
    const float* feat    = (const float*)d_in[0];
    const float* boxes   = (const float*)d_in[1];
    const int*   box_ids = (const int*)d_in[2];
    const int*   cls     = (const int*)d_in[3];
    const float* c1w     = (const float*)d_in[4];
    const float* c1b     = (const float*)d_in[5];
    const float* c2w     = (const float*)d_in[6];
    const float* c2b     = (const float*)d_in[7];
    const float* ow      = (const float*)d_in[8];
    const float* ob      = (const float*)d_in[9];

    unsigned short* wt1  = (unsigned short*)d_ws;
    unsigned short* wt2  = wt1 + 36864;
    unsigned short* wto  = wt2 + 36864;
    int*            perm = (int*)(wto + 9216);
    unsigned short* bufA = (unsigned short*)(perm + 1024);

    // single bf16 [nc][32][32][64] buffer in ws; nc as large as fits (pref 1024)
    size_t wt_bytes = (size_t)(36864 * 2 + 9216) * 2 + 4096;
    size_t avail = (ws_size > wt_bytes) ? (ws_size - wt_bytes) : 0;
    size_t per_box = (size_t)32 * 32 * 64 * 2;
    int nc = (int)(avail / per_box);
    if (nc >= NB) nc = NB;
    else {
        int p = 1;
        while (p * 2 <= nc) p *= 2;
        nc = (p < 1) ? 1 : p;
    }

    sort_kernel<<<1, 1024, 0, stream>>>(box_ids, perm);
    wprep_kernel<<<324, 256, 0, stream>>>(c1w, c2w, ow, wt1, wt2, wto);

    for (int nn0 = 0; nn0 < NB; nn0 += nc) {
        int cur = (NB - nn0 < nc) ? (NB - nn0) : nc;
        int nblk = 4 * cur;
        crop_conv1_kernel<<<nblk, 256, 0, stream>>>(feat, boxes, box_ids, perm,
                                                    wt1, c1b, bufA, nn0, nblk);
        conv2_out_kernel<<<nblk, 256, 0, stream>>>(bufA, wt2, c2b, wto, ob,
                                                   cls, perm, (float*)d_out, nn0, nblk);
    }
}